// Round 5
// baseline (193.435 us; speedup 1.0000x reference)
//
#include <hip/hip_runtime.h>
#include <hip/hip_fp16.h>

#define N_NODES 50000
#define N_EDGES 800000
#define HALF_E  400000
#define IN_F    128
#define OUT_F   32
#define HEADS   4
#define EDGE_DIM 8
#define LRELU_ALPHA 0.2f

#define SCAN_BLK 1024
#define N_SCAN_BLKS ((N_NODES + SCAN_BLK - 1) / SCAN_BLK)  // 49

// round-to-nearest-even f32 -> bf16 (as ushort in low bits)
__device__ __forceinline__ unsigned f2bf(float f) {
  unsigned u = __float_as_uint(f);
  return (u + 0x7fffu + ((u >> 16) & 1u)) >> 16;
}

// ---------------------------------------------------------------------------
// K1: LDS-tiled fp32 GEMM. xt[n,ho] = sum_i x[n,i] * W[h,i,o], 64 nodes/block.
// Output xt stored as packed bf16 pairs: xtb[n*64 + k] = features (2k, 2k+1).
// Epilogue: fused alpha_src/alpha_dst reduction (fp32, unaffected by bf16).
// ---------------------------------------------------------------------------
__global__ __launch_bounds__(256) void k_transform(
    const float* __restrict__ x, const float* __restrict__ W,
    const float* __restrict__ a, unsigned* __restrict__ xtb,
    float* __restrict__ alpha_src, float* __restrict__ alpha_dst) {
  __shared__ float sx[64][128];
  const int t = threadIdx.x;
  const int n0 = blockIdx.x * 64;

  // stage x tile (coalesced float4)
#pragma unroll
  for (int r = 0; r < 8; ++r) {
    const int f = r * 256 + t;   // float4 index within 64x128 tile
    const int node = f >> 5;
    const int i4 = (f & 31) * 4;
    const int n = n0 + node;
    float4 v = make_float4(0.f, 0.f, 0.f, 0.f);
    if (n < N_NODES) v = *reinterpret_cast<const float4*>(&x[(size_t)n * 128 + i4]);
    *reinterpret_cast<float4*>(&sx[node][i4]) = v;
  }
  __syncthreads();

  const int lane31 = t & 31;
  const int ng = t >> 5;          // node group 0..7
  const int ho0 = lane31 * 4;     // 4 consecutive output columns
  const int h = ho0 >> 5;
  const int o0 = ho0 & 31;

  float acc[8][4];
#pragma unroll
  for (int nd = 0; nd < 8; ++nd)
#pragma unroll
    for (int j = 0; j < 4; ++j) acc[nd][j] = 0.f;

  const float* __restrict__ wp = W + h * (IN_F * OUT_F) + o0;
#pragma unroll 4
  for (int i = 0; i < IN_F; ++i) {
    const float4 wv = *reinterpret_cast<const float4*>(&wp[i * OUT_F]);
#pragma unroll
    for (int nd = 0; nd < 8; ++nd) {
      const float xv = sx[ng * 8 + nd][i];
      acc[nd][0] = fmaf(xv, wv.x, acc[nd][0]);
      acc[nd][1] = fmaf(xv, wv.y, acc[nd][1]);
      acc[nd][2] = fmaf(xv, wv.z, acc[nd][2]);
      acc[nd][3] = fmaf(xv, wv.w, acc[nd][3]);
    }
  }

  // store xt as packed bf16 (8 B per thread per node)
#pragma unroll
  for (int nd = 0; nd < 8; ++nd) {
    const int n = n0 + ng * 8 + nd;
    if (n < N_NODES) {
      uint2 pk;
      pk.x = f2bf(acc[nd][0]) | (f2bf(acc[nd][1]) << 16);
      pk.y = f2bf(acc[nd][2]) | (f2bf(acc[nd][3]) << 16);
      *reinterpret_cast<uint2*>(&xtb[(size_t)n * 64 + lane31 * 2]) = pk;
    }
  }

  // fused alpha reduction: alpha_*[n,h] = sum_o xt[n,h,o] * a_*[h,o]
  const float4 as4 = *reinterpret_cast<const float4*>(&a[h * 72 + o0]);
  const float4 ad4 = *reinterpret_cast<const float4*>(&a[h * 72 + 32 + o0]);
#pragma unroll
  for (int nd = 0; nd < 8; ++nd) {
    float s = acc[nd][0] * as4.x + acc[nd][1] * as4.y + acc[nd][2] * as4.z +
              acc[nd][3] * as4.w;
    float d = acc[nd][0] * ad4.x + acc[nd][1] * ad4.y + acc[nd][2] * ad4.z +
              acc[nd][3] * ad4.w;
    s += __shfl_xor(s, 1, 64); d += __shfl_xor(d, 1, 64);
    s += __shfl_xor(s, 2, 64); d += __shfl_xor(d, 2, 64);
    s += __shfl_xor(s, 4, 64); d += __shfl_xor(d, 4, 64);
    if ((t & 7) == 0) {
      const int n = n0 + ng * 8 + nd;
      if (n < N_NODES) {
        alpha_src[n * 4 + h] = s;
        alpha_dst[n * 4 + h] = d;
      }
    }
  }
}

// ---------------------------------------------------------------------------
// K2: histogram of dst
// ---------------------------------------------------------------------------
__global__ __launch_bounds__(256) void k_hist(const int* __restrict__ ei,
                                              unsigned* __restrict__ count) {
  const int e = blockIdx.x * blockDim.x + threadIdx.x;
  if (e >= N_EDGES) return;
  atomicAdd(&count[ei[N_EDGES + e]], 1u);
}

// ---------------------------------------------------------------------------
// K3a/b/c: hierarchical exclusive scan of count[] -> row_start[]
// ---------------------------------------------------------------------------
__global__ __launch_bounds__(SCAN_BLK) void k_scan_a(
    const unsigned* __restrict__ cnt, unsigned* __restrict__ rs,
    unsigned* __restrict__ bsum) {
  __shared__ unsigned wpre[16];
  const int t = threadIdx.x;
  const int i = blockIdx.x * SCAN_BLK + t;
  const int lane = t & 63;
  const int wid = t >> 6;
  unsigned v = (i < N_NODES) ? cnt[i] : 0u;
  unsigned incl = v;
#pragma unroll
  for (int off = 1; off < 64; off <<= 1) {
    unsigned n = __shfl_up(incl, off, 64);
    if (lane >= off) incl += n;
  }
  if (lane == 63) wpre[wid] = incl;
  __syncthreads();
  if (t < 16) {
    unsigned wv = wpre[t];
    unsigned wincl = wv;
#pragma unroll
    for (int off = 1; off < 16; off <<= 1) {
      unsigned n = __shfl_up(wincl, off, 64);
      if (t >= off) wincl += n;
    }
    wpre[t] = wincl - wv;  // exclusive wave prefix
    if (t == 15) bsum[blockIdx.x] = wincl;  // block total
  }
  __syncthreads();
  if (i < N_NODES) rs[i] = incl - v + wpre[wid];
}

__global__ __launch_bounds__(64) void k_scan_b(unsigned* __restrict__ bsum,
                                               unsigned* __restrict__ boff) {
  const int t = threadIdx.x;
  unsigned v = (t < N_SCAN_BLKS) ? bsum[t] : 0u;
  unsigned incl = v;
#pragma unroll
  for (int off = 1; off < 64; off <<= 1) {
    unsigned n = __shfl_up(incl, off, 64);
    if (t >= off) incl += n;
  }
  if (t < N_SCAN_BLKS) boff[t] = incl - v;
}

__global__ __launch_bounds__(SCAN_BLK) void k_scan_c(
    unsigned* __restrict__ rs, const unsigned* __restrict__ boff) {
  const int i = blockIdx.x * SCAN_BLK + threadIdx.x;
  if (i < N_NODES) rs[i] += boff[i >> 10];
  if (i == 0) rs[N_NODES] = N_EDGES;
}

// ---------------------------------------------------------------------------
// K4: scatter edges into CSR slots. One packed 16B entry per edge:
//   {src, fp16x2(s0,s1), fp16x2(s2,s3), 0}
// 2 edges per thread (split-half striding) for doubled MLP on atomic+store.
// ---------------------------------------------------------------------------
__device__ __forceinline__ uint4 make_entry(
    int e, int src, int dst, const float* __restrict__ ea,
    const float* __restrict__ a, const float* __restrict__ alpha_src,
    const float* __restrict__ alpha_dst) {
  const float4 ev0 = *reinterpret_cast<const float4*>(&ea[(size_t)e * EDGE_DIM]);
  const float4 ev1 = *reinterpret_cast<const float4*>(&ea[(size_t)e * EDGE_DIM + 4]);
  const float4 als = *reinterpret_cast<const float4*>(&alpha_src[src * 4]);
  const float4 ald = *reinterpret_cast<const float4*>(&alpha_dst[dst * 4]);
  const float* alsp = reinterpret_cast<const float*>(&als);
  const float* aldp = reinterpret_cast<const float*>(&ald);
  unsigned sh[4];
#pragma unroll
  for (int h = 0; h < HEADS; ++h) {
    float s = alsp[h] + aldp[h];
    const float* ae = &a[h * 72 + 64];
    s = fmaf(ev0.x, ae[0], s);
    s = fmaf(ev0.y, ae[1], s);
    s = fmaf(ev0.z, ae[2], s);
    s = fmaf(ev0.w, ae[3], s);
    s = fmaf(ev1.x, ae[4], s);
    s = fmaf(ev1.y, ae[5], s);
    s = fmaf(ev1.z, ae[6], s);
    s = fmaf(ev1.w, ae[7], s);
    s = s > 0.f ? s : LRELU_ALPHA * s;
    sh[h] = (unsigned)__half_as_ushort(__float2half(s));
  }
  uint4 ent;
  ent.x = (unsigned)src;
  ent.y = sh[0] | (sh[1] << 16);
  ent.z = sh[2] | (sh[3] << 16);
  ent.w = 0u;
  return ent;
}

__global__ __launch_bounds__(256) void k_scatter(
    const int* __restrict__ ei, const float* __restrict__ ea,
    const float* __restrict__ a, const float* __restrict__ alpha_src,
    const float* __restrict__ alpha_dst, const unsigned* __restrict__ rs,
    unsigned* __restrict__ fill, uint4* __restrict__ csr) {
  const int e0 = blockIdx.x * blockDim.x + threadIdx.x;
  if (e0 >= HALF_E) return;
  const int e1 = e0 + HALF_E;

  const int src0 = ei[e0];
  const int dst0 = ei[N_EDGES + e0];
  const int src1 = ei[e1];
  const int dst1 = ei[N_EDGES + e1];

  const uint4 ent0 = make_entry(e0, src0, dst0, ea, a, alpha_src, alpha_dst);
  const uint4 ent1 = make_entry(e1, src1, dst1, ea, a, alpha_src, alpha_dst);

  // both tickets in flight together
  const unsigned pos0 = atomicAdd(&fill[dst0], 1u);
  const unsigned pos1 = atomicAdd(&fill[dst1], 1u);

  csr[rs[dst0] + pos0] = ent0;
  csr[rs[dst1] + pos1] = ent1;
}

// ---------------------------------------------------------------------------
// K5: one wave per dst. Lane-parallel softmax over CSR-contiguous packed
// entries (score of edge j0+(l>>2), head l&3 per lane), then batched gather:
// 16 edges/round, w and src broadcast via shfl, 16 independent bf16 gathers.
// lane l accumulates features 2l, 2l+1 (head l>>4).
// ---------------------------------------------------------------------------
__device__ __forceinline__ float ent_score(const uint4& ent, int hA) {
  const unsigned uu = (hA < 2) ? ent.y : ent.z;
  const unsigned us = (hA & 1) ? (uu >> 16) : (uu & 0xffffu);
  return __half2float(__ushort_as_half((unsigned short)us));
}

__global__ __launch_bounds__(256) void k_agg(
    const unsigned* __restrict__ rs, const uint4* __restrict__ csr,
    const unsigned* __restrict__ xtb, float* __restrict__ out) {
  const int lane = threadIdx.x & 63;
  const int dst = (int)((blockIdx.x * (unsigned)blockDim.x + threadIdx.x) >> 6);
  if (dst >= N_NODES) return;

  const unsigned j0 = rs[dst];
  const unsigned j1 = rs[dst + 1];
  const int deg = (int)(j1 - j0);

  float a0 = 0.f, a1 = 0.f, lsum = 0.f;

  if (deg > 0) {
    const int rounds = (deg + 15) >> 4;
    const int sub = lane >> 2;   // edge-within-round in score space
    const int hA = lane & 3;     // head in score space
    const int hB = lane >> 4;    // head of this lane's output features

    // pass 1: per-head max
    float m = -INFINITY;
    for (int r = 0; r < rounds; ++r) {
      const int j = (int)j0 + r * 16 + sub;
      if (j < (int)j1) m = fmaxf(m, ent_score(csr[j], hA));
    }
    m = fmaxf(m, __shfl_xor(m, 4, 64));
    m = fmaxf(m, __shfl_xor(m, 8, 64));
    m = fmaxf(m, __shfl_xor(m, 16, 64));
    m = fmaxf(m, __shfl_xor(m, 32, 64));

    // pass 2: weights + batched gather-accumulate
    for (int r = 0; r < rounds; ++r) {
      const int base = (int)j0 + r * 16;
      const int j = base + sub;
      const float s = (j < (int)j1) ? ent_score(csr[j], hA) : -INFINITY;
      const float w = __expf(s - m);   // padded lanes: exp(-inf)=0
      lsum += w;
      const int jc = base + (lane & 15);
      const int srcv = (jc < (int)j1) ? (int)csr[jc].x : 0;
      const int nedge = min(16, deg - r * 16);
#pragma unroll 4
      for (int jj = 0; jj < nedge; ++jj) {
        const int src = __shfl(srcv, jj, 64);
        const float wj = __shfl(w, 4 * jj + hB, 64);
        const unsigned u = xtb[(size_t)src * 64 + lane];
        a0 = fmaf(wj, __uint_as_float(u << 16), a0);
        a1 = fmaf(wj, __uint_as_float(u & 0xffff0000u), a1);
      }
    }
    lsum += __shfl_xor(lsum, 4, 64);
    lsum += __shfl_xor(lsum, 8, 64);
    lsum += __shfl_xor(lsum, 16, 64);
    lsum += __shfl_xor(lsum, 32, 64);
    lsum = __shfl(lsum, hB, 64);   // lane hB holds head hB's sum
  }

  const float inv = 1.0f / (lsum + 1e-10f);
  out[(size_t)dst * 128 + lane * 2 + 0] = a0 * inv;
  out[(size_t)dst * 128 + lane * 2 + 1] = a1 * inv;
}

extern "C" void kernel_launch(void* const* d_in, const int* in_sizes, int n_in,
                              void* d_out, int out_size, void* d_ws,
                              size_t ws_size, hipStream_t stream) {
  const float* x = (const float*)d_in[0];
  const int* ei = (const int*)d_in[1];
  const float* ea = (const float*)d_in[2];
  const float* W = (const float*)d_in[3];
  const float* a = (const float*)d_in[4];
  float* out = (float*)d_out;

  // workspace layout
  char* p = (char*)d_ws;
  unsigned* xtb = (unsigned*)p;     p += (size_t)N_NODES * 64 * 4;    // 12.8 MB
  uint4* csr = (uint4*)p;           p += (size_t)N_EDGES * 16;        // 12.8 MB
  float* alpha_src = (float*)p;     p += (size_t)N_NODES * 4 * 4;     // 0.8 MB
  float* alpha_dst = (float*)p;     p += (size_t)N_NODES * 4 * 4;     // 0.8 MB
  unsigned* count = (unsigned*)p;   p += (size_t)N_NODES * 4;         // 0.2 MB
  unsigned* fill = (unsigned*)p;    p += (size_t)N_NODES * 4;         // 0.2 MB
  unsigned* rs = (unsigned*)p;      p += (size_t)(N_NODES + 1) * 4;
  unsigned* bsum = (unsigned*)p;    p += 64 * 4;
  unsigned* boff = (unsigned*)p;    p += 64 * 4;

  // zero count+fill (contiguous)
  hipMemsetAsync(count, 0, (size_t)N_NODES * 4 * 2, stream);

  k_transform<<<(N_NODES + 63) / 64, 256, 0, stream>>>(x, W, a, xtb, alpha_src,
                                                       alpha_dst);
  k_hist<<<(N_EDGES + 255) / 256, 256, 0, stream>>>(ei, count);
  k_scan_a<<<N_SCAN_BLKS, SCAN_BLK, 0, stream>>>(count, rs, bsum);
  k_scan_b<<<1, 64, 0, stream>>>(bsum, boff);
  k_scan_c<<<N_SCAN_BLKS, SCAN_BLK, 0, stream>>>(rs, boff);
  k_scatter<<<(HALF_E + 255) / 256, 256, 0, stream>>>(
      ei, ea, a, alpha_src, alpha_dst, rs, fill, csr);
  k_agg<<<(N_NODES * 64 + 255) / 256, 256, 0, stream>>>(rs, csr, xtb, out);
}

// Round 6
// 171.949 us; speedup vs baseline: 1.1250x; 1.1250x over previous
//
#include <hip/hip_runtime.h>
#include <hip/hip_fp16.h>

#define N_NODES 50000
#define N_EDGES 800000
#define QUART_E 200000
#define IN_F    128
#define OUT_F   32
#define HEADS   4
#define EDGE_DIM 8
#define LRELU_ALPHA 0.2f

#define SCAN_BLK 1024
#define N_SCAN_BLKS ((N_NODES + SCAN_BLK - 1) / SCAN_BLK)  // 49

// round-to-nearest-even f32 -> bf16 (as ushort in low bits)
__device__ __forceinline__ unsigned f2bf(float f) {
  unsigned u = __float_as_uint(f);
  return (u + 0x7fffu + ((u >> 16) & 1u)) >> 16;
}

// ---------------------------------------------------------------------------
// K1: LDS-tiled fp32 GEMM. xt[n,ho] = sum_i x[n,i] * W[h,i,o], 64 nodes/block.
// Output xt stored as packed bf16 pairs: xtb[n*64 + k] = features (2k, 2k+1).
// Epilogue: fused alpha_src/alpha_dst reduction (fp32).
// ---------------------------------------------------------------------------
__global__ __launch_bounds__(256) void k_transform(
    const float* __restrict__ x, const float* __restrict__ W,
    const float* __restrict__ a, unsigned* __restrict__ xtb,
    float* __restrict__ alpha_src, float* __restrict__ alpha_dst) {
  __shared__ float sx[64][128];
  const int t = threadIdx.x;
  const int n0 = blockIdx.x * 64;

  // stage x tile (coalesced float4)
#pragma unroll
  for (int r = 0; r < 8; ++r) {
    const int f = r * 256 + t;   // float4 index within 64x128 tile
    const int node = f >> 5;
    const int i4 = (f & 31) * 4;
    const int n = n0 + node;
    float4 v = make_float4(0.f, 0.f, 0.f, 0.f);
    if (n < N_NODES) v = *reinterpret_cast<const float4*>(&x[(size_t)n * 128 + i4]);
    *reinterpret_cast<float4*>(&sx[node][i4]) = v;
  }
  __syncthreads();

  const int lane31 = t & 31;
  const int ng = t >> 5;          // node group 0..7
  const int ho0 = lane31 * 4;     // 4 consecutive output columns
  const int h = ho0 >> 5;
  const int o0 = ho0 & 31;

  float acc[8][4];
#pragma unroll
  for (int nd = 0; nd < 8; ++nd)
#pragma unroll
    for (int j = 0; j < 4; ++j) acc[nd][j] = 0.f;

  const float* __restrict__ wp = W + h * (IN_F * OUT_F) + o0;
#pragma unroll 4
  for (int i = 0; i < IN_F; ++i) {
    const float4 wv = *reinterpret_cast<const float4*>(&wp[i * OUT_F]);
#pragma unroll
    for (int nd = 0; nd < 8; ++nd) {
      const float xv = sx[ng * 8 + nd][i];
      acc[nd][0] = fmaf(xv, wv.x, acc[nd][0]);
      acc[nd][1] = fmaf(xv, wv.y, acc[nd][1]);
      acc[nd][2] = fmaf(xv, wv.z, acc[nd][2]);
      acc[nd][3] = fmaf(xv, wv.w, acc[nd][3]);
    }
  }

  // store xt as packed bf16 (8 B per thread per node)
#pragma unroll
  for (int nd = 0; nd < 8; ++nd) {
    const int n = n0 + ng * 8 + nd;
    if (n < N_NODES) {
      uint2 pk;
      pk.x = f2bf(acc[nd][0]) | (f2bf(acc[nd][1]) << 16);
      pk.y = f2bf(acc[nd][2]) | (f2bf(acc[nd][3]) << 16);
      *reinterpret_cast<uint2*>(&xtb[(size_t)n * 64 + lane31 * 2]) = pk;
    }
  }

  // fused alpha reduction: alpha_*[n,h] = sum_o xt[n,h,o] * a_*[h,o]
  const float4 as4 = *reinterpret_cast<const float4*>(&a[h * 72 + o0]);
  const float4 ad4 = *reinterpret_cast<const float4*>(&a[h * 72 + 32 + o0]);
#pragma unroll
  for (int nd = 0; nd < 8; ++nd) {
    float s = acc[nd][0] * as4.x + acc[nd][1] * as4.y + acc[nd][2] * as4.z +
              acc[nd][3] * as4.w;
    float d = acc[nd][0] * ad4.x + acc[nd][1] * ad4.y + acc[nd][2] * ad4.z +
              acc[nd][3] * ad4.w;
    s += __shfl_xor(s, 1, 64); d += __shfl_xor(d, 1, 64);
    s += __shfl_xor(s, 2, 64); d += __shfl_xor(d, 2, 64);
    s += __shfl_xor(s, 4, 64); d += __shfl_xor(d, 4, 64);
    if ((t & 7) == 0) {
      const int n = n0 + ng * 8 + nd;
      if (n < N_NODES) {
        alpha_src[n * 4 + h] = s;
        alpha_dst[n * 4 + h] = d;
      }
    }
  }
}

// ---------------------------------------------------------------------------
// K2: histogram of dst
// ---------------------------------------------------------------------------
__global__ __launch_bounds__(256) void k_hist(const int* __restrict__ ei,
                                              unsigned* __restrict__ count) {
  const int e = blockIdx.x * blockDim.x + threadIdx.x;
  if (e >= N_EDGES) return;
  atomicAdd(&count[ei[N_EDGES + e]], 1u);
}

// ---------------------------------------------------------------------------
// K3a/b/c: hierarchical exclusive scan of count[] -> row_start[]
// ---------------------------------------------------------------------------
__global__ __launch_bounds__(SCAN_BLK) void k_scan_a(
    const unsigned* __restrict__ cnt, unsigned* __restrict__ rs,
    unsigned* __restrict__ bsum) {
  __shared__ unsigned wpre[16];
  const int t = threadIdx.x;
  const int i = blockIdx.x * SCAN_BLK + t;
  const int lane = t & 63;
  const int wid = t >> 6;
  unsigned v = (i < N_NODES) ? cnt[i] : 0u;
  unsigned incl = v;
#pragma unroll
  for (int off = 1; off < 64; off <<= 1) {
    unsigned n = __shfl_up(incl, off, 64);
    if (lane >= off) incl += n;
  }
  if (lane == 63) wpre[wid] = incl;
  __syncthreads();
  if (t < 16) {
    unsigned wv = wpre[t];
    unsigned wincl = wv;
#pragma unroll
    for (int off = 1; off < 16; off <<= 1) {
      unsigned n = __shfl_up(wincl, off, 64);
      if (t >= off) wincl += n;
    }
    wpre[t] = wincl - wv;  // exclusive wave prefix
    if (t == 15) bsum[blockIdx.x] = wincl;  // block total
  }
  __syncthreads();
  if (i < N_NODES) rs[i] = incl - v + wpre[wid];
}

__global__ __launch_bounds__(64) void k_scan_b(unsigned* __restrict__ bsum,
                                               unsigned* __restrict__ boff) {
  const int t = threadIdx.x;
  unsigned v = (t < N_SCAN_BLKS) ? bsum[t] : 0u;
  unsigned incl = v;
#pragma unroll
  for (int off = 1; off < 64; off <<= 1) {
    unsigned n = __shfl_up(incl, off, 64);
    if (t >= off) incl += n;
  }
  if (t < N_SCAN_BLKS) boff[t] = incl - v;
}

__global__ __launch_bounds__(SCAN_BLK) void k_scan_c(
    unsigned* __restrict__ rs, const unsigned* __restrict__ boff) {
  const int i = blockIdx.x * SCAN_BLK + threadIdx.x;
  if (i < N_NODES) rs[i] += boff[i >> 10];
  if (i == 0) rs[N_NODES] = N_EDGES;
}

// ---------------------------------------------------------------------------
// K4: scatter edges into CSR slots. One packed 16B entry per edge:
//   {src, fp16x2(s0,s1), fp16x2(s2,s3), 0}
// 4 edges per thread; all atomic tickets + rs loads issued before entry
// computation so the scatter round-trips overlap the score math.
// ---------------------------------------------------------------------------
__device__ __forceinline__ uint4 make_entry(
    int e, int src, int dst, const float* __restrict__ ea,
    const float* __restrict__ a, const float* __restrict__ alpha_src,
    const float* __restrict__ alpha_dst) {
  const float4 ev0 = *reinterpret_cast<const float4*>(&ea[(size_t)e * EDGE_DIM]);
  const float4 ev1 = *reinterpret_cast<const float4*>(&ea[(size_t)e * EDGE_DIM + 4]);
  const float4 als = *reinterpret_cast<const float4*>(&alpha_src[src * 4]);
  const float4 ald = *reinterpret_cast<const float4*>(&alpha_dst[dst * 4]);
  const float* alsp = reinterpret_cast<const float*>(&als);
  const float* aldp = reinterpret_cast<const float*>(&ald);
  unsigned sh[4];
#pragma unroll
  for (int h = 0; h < HEADS; ++h) {
    float s = alsp[h] + aldp[h];
    const float* ae = &a[h * 72 + 64];
    s = fmaf(ev0.x, ae[0], s);
    s = fmaf(ev0.y, ae[1], s);
    s = fmaf(ev0.z, ae[2], s);
    s = fmaf(ev0.w, ae[3], s);
    s = fmaf(ev1.x, ae[4], s);
    s = fmaf(ev1.y, ae[5], s);
    s = fmaf(ev1.z, ae[6], s);
    s = fmaf(ev1.w, ae[7], s);
    s = s > 0.f ? s : LRELU_ALPHA * s;
    sh[h] = (unsigned)__half_as_ushort(__float2half(s));
  }
  uint4 ent;
  ent.x = (unsigned)src;
  ent.y = sh[0] | (sh[1] << 16);
  ent.z = sh[2] | (sh[3] << 16);
  ent.w = 0u;
  return ent;
}

__global__ __launch_bounds__(256) void k_scatter(
    const int* __restrict__ ei, const float* __restrict__ ea,
    const float* __restrict__ a, const float* __restrict__ alpha_src,
    const float* __restrict__ alpha_dst, const unsigned* __restrict__ rs,
    unsigned* __restrict__ fill, uint4* __restrict__ csr) {
  const int e0 = blockIdx.x * blockDim.x + threadIdx.x;
  if (e0 >= QUART_E) return;

  int e[4], src[4], dst[4];
#pragma unroll
  for (int i = 0; i < 4; ++i) {
    e[i] = e0 + i * QUART_E;
    src[i] = ei[e[i]];
    dst[i] = ei[N_EDGES + e[i]];
  }

  // issue all tickets + row starts up front (independent round-trips)
  unsigned pos[4], base[4];
#pragma unroll
  for (int i = 0; i < 4; ++i) pos[i] = atomicAdd(&fill[dst[i]], 1u);
#pragma unroll
  for (int i = 0; i < 4; ++i) base[i] = rs[dst[i]];

  uint4 ent[4];
#pragma unroll
  for (int i = 0; i < 4; ++i)
    ent[i] = make_entry(e[i], src[i], dst[i], ea, a, alpha_src, alpha_dst);

#pragma unroll
  for (int i = 0; i < 4; ++i) csr[base[i] + pos[i]] = ent[i];
}

// ---------------------------------------------------------------------------
// K5: one wave per dst. Single pass (no max subtraction — algebraically
// identical softmax; scores are O(1) so exp() cannot overflow fp32).
// Lane l reads packed entry j0+(l>>2), extracts head l&3; weights and src
// broadcast via shfl; full-16 unrolled gather (pad lanes w=0, src=0 ->
// row-0 gather is L1-resident and contributes exactly 0).
// lane l accumulates features 2l, 2l+1 (head l>>4).
// ---------------------------------------------------------------------------
__device__ __forceinline__ float ent_score(const uint4& ent, int hA) {
  const unsigned uu = (hA < 2) ? ent.y : ent.z;
  const unsigned us = (hA & 1) ? (uu >> 16) : (uu & 0xffffu);
  return __half2float(__ushort_as_half((unsigned short)us));
}

__global__ __launch_bounds__(256) void k_agg(
    const unsigned* __restrict__ rs, const uint4* __restrict__ csr,
    const unsigned* __restrict__ xtb, float* __restrict__ out) {
  const int lane = threadIdx.x & 63;
  const int dst = (int)((blockIdx.x * (unsigned)blockDim.x + threadIdx.x) >> 6);
  if (dst >= N_NODES) return;

  const unsigned j0 = rs[dst];
  const unsigned j1 = rs[dst + 1];
  const int deg = (int)(j1 - j0);

  float a0 = 0.f, a1 = 0.f, lsum = 0.f;

  if (deg > 0) {
    const int rounds = (deg + 15) >> 4;
    const int sub = lane >> 2;   // edge-within-round in score space
    const int hA = lane & 3;     // head in score space
    const int hB = lane >> 4;    // head of this lane's output features

    for (int r = 0; r < rounds; ++r) {
      const int base = (int)j0 + r * 16;
      const int j = base + sub;
      uint4 ent;
      if (j < (int)j1) {
        ent = csr[j];
      } else {
        ent.x = 0u; ent.y = 0xfc00fc00u; ent.z = 0xfc00fc00u; ent.w = 0u;
      }
      const float w = __expf(ent_score(ent, hA));  // pad: exp(-inf)=0
      lsum += w;
      const int sx = (int)ent.x;
#pragma unroll
      for (int jj = 0; jj < 16; ++jj) {
        const int src = __shfl(sx, 4 * jj, 64);
        const float wj = __shfl(w, 4 * jj + hB, 64);
        const unsigned u = xtb[(size_t)src * 64 + lane];
        a0 = fmaf(wj, __uint_as_float(u << 16), a0);
        a1 = fmaf(wj, __uint_as_float(u & 0xffff0000u), a1);
      }
    }
    lsum += __shfl_xor(lsum, 4, 64);
    lsum += __shfl_xor(lsum, 8, 64);
    lsum += __shfl_xor(lsum, 16, 64);
    lsum += __shfl_xor(lsum, 32, 64);
    lsum = __shfl(lsum, hB, 64);   // lane hB holds head hB's sum
  }

  const float inv = 1.0f / (lsum + 1e-10f);
  out[(size_t)dst * 128 + lane * 2 + 0] = a0 * inv;
  out[(size_t)dst * 128 + lane * 2 + 1] = a1 * inv;
}

extern "C" void kernel_launch(void* const* d_in, const int* in_sizes, int n_in,
                              void* d_out, int out_size, void* d_ws,
                              size_t ws_size, hipStream_t stream) {
  const float* x = (const float*)d_in[0];
  const int* ei = (const int*)d_in[1];
  const float* ea = (const float*)d_in[2];
  const float* W = (const float*)d_in[3];
  const float* a = (const float*)d_in[4];
  float* out = (float*)d_out;

  // workspace layout
  char* p = (char*)d_ws;
  unsigned* xtb = (unsigned*)p;     p += (size_t)N_NODES * 64 * 4;    // 12.8 MB
  uint4* csr = (uint4*)p;           p += (size_t)N_EDGES * 16;        // 12.8 MB
  float* alpha_src = (float*)p;     p += (size_t)N_NODES * 4 * 4;     // 0.8 MB
  float* alpha_dst = (float*)p;     p += (size_t)N_NODES * 4 * 4;     // 0.8 MB
  unsigned* count = (unsigned*)p;   p += (size_t)N_NODES * 4;         // 0.2 MB
  unsigned* fill = (unsigned*)p;    p += (size_t)N_NODES * 4;         // 0.2 MB
  unsigned* rs = (unsigned*)p;      p += (size_t)(N_NODES + 1) * 4;
  unsigned* bsum = (unsigned*)p;    p += 64 * 4;
  unsigned* boff = (unsigned*)p;    p += 64 * 4;

  // zero count+fill (contiguous)
  hipMemsetAsync(count, 0, (size_t)N_NODES * 4 * 2, stream);

  k_transform<<<(N_NODES + 63) / 64, 256, 0, stream>>>(x, W, a, xtb, alpha_src,
                                                       alpha_dst);
  k_hist<<<(N_EDGES + 255) / 256, 256, 0, stream>>>(ei, count);
  k_scan_a<<<N_SCAN_BLKS, SCAN_BLK, 0, stream>>>(count, rs, bsum);
  k_scan_b<<<1, 64, 0, stream>>>(bsum, boff);
  k_scan_c<<<N_SCAN_BLKS, SCAN_BLK, 0, stream>>>(rs, boff);
  k_scatter<<<(QUART_E + 255) / 256, 256, 0, stream>>>(
      ei, ea, a, alpha_src, alpha_dst, rs, fill, csr);
  k_agg<<<(N_NODES * 64 + 255) / 256, 256, 0, stream>>>(rs, csr, xtb, out);
}

// Round 7
// 159.288 us; speedup vs baseline: 1.2144x; 1.0795x over previous
//
#include <hip/hip_runtime.h>
#include <hip/hip_fp16.h>

#define N_NODES 50000
#define N_EDGES 800000
#define IN_F    128
#define OUT_F   32
#define HEADS   4
#define EDGE_DIM 8
#define LRELU_ALPHA 0.2f

#define SCAN_BLK 1024
#define N_SCAN_BLKS ((N_NODES + SCAN_BLK - 1) / SCAN_BLK)  // 49

// round-to-nearest-even f32 -> bf16 (as ushort in low bits)
__device__ __forceinline__ unsigned f2bf(float f) {
  unsigned u = __float_as_uint(f);
  return (u + 0x7fffu + ((u >> 16) & 1u)) >> 16;
}

// ---------------------------------------------------------------------------
// K1: LDS-tiled fp32 GEMM. xt[n,ho] = sum_i x[n,i] * W[h,i,o], 64 nodes/block.
// Output xt stored as packed bf16 pairs: xtb[n*64 + k] = features (2k, 2k+1).
// Epilogue: fused alpha_src/alpha_dst reduction (fp32).
// ---------------------------------------------------------------------------
__global__ __launch_bounds__(256) void k_transform(
    const float* __restrict__ x, const float* __restrict__ W,
    const float* __restrict__ a, unsigned* __restrict__ xtb,
    float* __restrict__ alpha_src, float* __restrict__ alpha_dst) {
  __shared__ float sx[64][128];
  const int t = threadIdx.x;
  const int n0 = blockIdx.x * 64;

  // stage x tile (coalesced float4)
#pragma unroll
  for (int r = 0; r < 8; ++r) {
    const int f = r * 256 + t;   // float4 index within 64x128 tile
    const int node = f >> 5;
    const int i4 = (f & 31) * 4;
    const int n = n0 + node;
    float4 v = make_float4(0.f, 0.f, 0.f, 0.f);
    if (n < N_NODES) v = *reinterpret_cast<const float4*>(&x[(size_t)n * 128 + i4]);
    *reinterpret_cast<float4*>(&sx[node][i4]) = v;
  }
  __syncthreads();

  const int lane31 = t & 31;
  const int ng = t >> 5;          // node group 0..7
  const int ho0 = lane31 * 4;     // 4 consecutive output columns
  const int h = ho0 >> 5;
  const int o0 = ho0 & 31;

  float acc[8][4];
#pragma unroll
  for (int nd = 0; nd < 8; ++nd)
#pragma unroll
    for (int j = 0; j < 4; ++j) acc[nd][j] = 0.f;

  const float* __restrict__ wp = W + h * (IN_F * OUT_F) + o0;
#pragma unroll 4
  for (int i = 0; i < IN_F; ++i) {
    const float4 wv = *reinterpret_cast<const float4*>(&wp[i * OUT_F]);
#pragma unroll
    for (int nd = 0; nd < 8; ++nd) {
      const float xv = sx[ng * 8 + nd][i];
      acc[nd][0] = fmaf(xv, wv.x, acc[nd][0]);
      acc[nd][1] = fmaf(xv, wv.y, acc[nd][1]);
      acc[nd][2] = fmaf(xv, wv.z, acc[nd][2]);
      acc[nd][3] = fmaf(xv, wv.w, acc[nd][3]);
    }
  }

  // store xt as packed bf16 (8 B per thread per node)
#pragma unroll
  for (int nd = 0; nd < 8; ++nd) {
    const int n = n0 + ng * 8 + nd;
    if (n < N_NODES) {
      uint2 pk;
      pk.x = f2bf(acc[nd][0]) | (f2bf(acc[nd][1]) << 16);
      pk.y = f2bf(acc[nd][2]) | (f2bf(acc[nd][3]) << 16);
      *reinterpret_cast<uint2*>(&xtb[(size_t)n * 64 + lane31 * 2]) = pk;
    }
  }

  // fused alpha reduction: alpha_*[n,h] = sum_o xt[n,h,o] * a_*[h,o]
  const float4 as4 = *reinterpret_cast<const float4*>(&a[h * 72 + o0]);
  const float4 ad4 = *reinterpret_cast<const float4*>(&a[h * 72 + 32 + o0]);
#pragma unroll
  for (int nd = 0; nd < 8; ++nd) {
    float s = acc[nd][0] * as4.x + acc[nd][1] * as4.y + acc[nd][2] * as4.z +
              acc[nd][3] * as4.w;
    float d = acc[nd][0] * ad4.x + acc[nd][1] * ad4.y + acc[nd][2] * ad4.z +
              acc[nd][3] * ad4.w;
    s += __shfl_xor(s, 1, 64); d += __shfl_xor(d, 1, 64);
    s += __shfl_xor(s, 2, 64); d += __shfl_xor(d, 2, 64);
    s += __shfl_xor(s, 4, 64); d += __shfl_xor(d, 4, 64);
    if ((t & 7) == 0) {
      const int n = n0 + ng * 8 + nd;
      if (n < N_NODES) {
        alpha_src[n * 4 + h] = s;
        alpha_dst[n * 4 + h] = d;
      }
    }
  }
}

// ---------------------------------------------------------------------------
// K2: histogram of dst
// ---------------------------------------------------------------------------
__global__ __launch_bounds__(256) void k_hist(const int* __restrict__ ei,
                                              unsigned* __restrict__ count) {
  const int e = blockIdx.x * blockDim.x + threadIdx.x;
  if (e >= N_EDGES) return;
  atomicAdd(&count[ei[N_EDGES + e]], 1u);
}

// ---------------------------------------------------------------------------
// K3a/b/c: hierarchical exclusive scan of count[] -> row_start[]
// k_scan_c also seeds fill[] = rs[] so the scatter atomic returns an
// absolute CSR slot (no rs gather in the hot scatter).
// ---------------------------------------------------------------------------
__global__ __launch_bounds__(SCAN_BLK) void k_scan_a(
    const unsigned* __restrict__ cnt, unsigned* __restrict__ rs,
    unsigned* __restrict__ bsum) {
  __shared__ unsigned wpre[16];
  const int t = threadIdx.x;
  const int i = blockIdx.x * SCAN_BLK + t;
  const int lane = t & 63;
  const int wid = t >> 6;
  unsigned v = (i < N_NODES) ? cnt[i] : 0u;
  unsigned incl = v;
#pragma unroll
  for (int off = 1; off < 64; off <<= 1) {
    unsigned n = __shfl_up(incl, off, 64);
    if (lane >= off) incl += n;
  }
  if (lane == 63) wpre[wid] = incl;
  __syncthreads();
  if (t < 16) {
    unsigned wv = wpre[t];
    unsigned wincl = wv;
#pragma unroll
    for (int off = 1; off < 16; off <<= 1) {
      unsigned n = __shfl_up(wincl, off, 64);
      if (t >= off) wincl += n;
    }
    wpre[t] = wincl - wv;  // exclusive wave prefix
    if (t == 15) bsum[blockIdx.x] = wincl;  // block total
  }
  __syncthreads();
  if (i < N_NODES) rs[i] = incl - v + wpre[wid];
}

__global__ __launch_bounds__(64) void k_scan_b(unsigned* __restrict__ bsum,
                                               unsigned* __restrict__ boff) {
  const int t = threadIdx.x;
  unsigned v = (t < N_SCAN_BLKS) ? bsum[t] : 0u;
  unsigned incl = v;
#pragma unroll
  for (int off = 1; off < 64; off <<= 1) {
    unsigned n = __shfl_up(incl, off, 64);
    if (t >= off) incl += n;
  }
  if (t < N_SCAN_BLKS) boff[t] = incl - v;
}

__global__ __launch_bounds__(SCAN_BLK) void k_scan_c(
    unsigned* __restrict__ rs, const unsigned* __restrict__ boff,
    unsigned* __restrict__ fill) {
  const int i = blockIdx.x * SCAN_BLK + threadIdx.x;
  if (i < N_NODES) {
    const unsigned v = rs[i] + boff[i >> 10];
    rs[i] = v;
    fill[i] = v;
  }
  if (i == 0) rs[N_NODES] = N_EDGES;
}

// ---------------------------------------------------------------------------
// K4: scatter edges into CSR slots. One packed 16B entry per edge:
//   {src, fp16x2(s0,s1), fp16x2(s2,s3), 0}
// 1 edge/thread (12500 waves -> saturated occupancy = max outstanding
// scatters); fill pre-seeded with rs so one atomic gives the absolute slot.
// ---------------------------------------------------------------------------
__device__ __forceinline__ uint4 make_entry(
    int e, int src, int dst, const float* __restrict__ ea,
    const float* __restrict__ a, const float* __restrict__ alpha_src,
    const float* __restrict__ alpha_dst) {
  const float4 ev0 = *reinterpret_cast<const float4*>(&ea[(size_t)e * EDGE_DIM]);
  const float4 ev1 = *reinterpret_cast<const float4*>(&ea[(size_t)e * EDGE_DIM + 4]);
  const float4 als = *reinterpret_cast<const float4*>(&alpha_src[src * 4]);
  const float4 ald = *reinterpret_cast<const float4*>(&alpha_dst[dst * 4]);
  const float* alsp = reinterpret_cast<const float*>(&als);
  const float* aldp = reinterpret_cast<const float*>(&ald);
  unsigned sh[4];
#pragma unroll
  for (int h = 0; h < HEADS; ++h) {
    float s = alsp[h] + aldp[h];
    const float* ae = &a[h * 72 + 64];
    s = fmaf(ev0.x, ae[0], s);
    s = fmaf(ev0.y, ae[1], s);
    s = fmaf(ev0.z, ae[2], s);
    s = fmaf(ev0.w, ae[3], s);
    s = fmaf(ev1.x, ae[4], s);
    s = fmaf(ev1.y, ae[5], s);
    s = fmaf(ev1.z, ae[6], s);
    s = fmaf(ev1.w, ae[7], s);
    s = s > 0.f ? s : LRELU_ALPHA * s;
    sh[h] = (unsigned)__half_as_ushort(__float2half(s));
  }
  uint4 ent;
  ent.x = (unsigned)src;
  ent.y = sh[0] | (sh[1] << 16);
  ent.z = sh[2] | (sh[3] << 16);
  ent.w = 0u;
  return ent;
}

__global__ __launch_bounds__(256) void k_scatter(
    const int* __restrict__ ei, const float* __restrict__ ea,
    const float* __restrict__ a, const float* __restrict__ alpha_src,
    const float* __restrict__ alpha_dst, unsigned* __restrict__ fill,
    uint4* __restrict__ csr) {
  const int e = blockIdx.x * blockDim.x + threadIdx.x;
  if (e >= N_EDGES) return;
  const int src = ei[e];
  const int dst = ei[N_EDGES + e];
  const unsigned slot = atomicAdd(&fill[dst], 1u);  // absolute CSR slot
  csr[slot] = make_entry(e, src, dst, ea, a, alpha_src, alpha_dst);
}

// ---------------------------------------------------------------------------
// K5: one wave per dst. Single pass (no max subtraction — algebraically
// identical softmax; scores are O(1) so exp() cannot overflow fp32).
// Lane l reads packed entry j0+(l>>2), extracts head l&3; weights and src
// broadcast via shfl; full-16 unrolled gather (pad lanes w=0, src=0 ->
// row-0 gather is L1-resident and contributes exactly 0).
// lane l accumulates features 2l, 2l+1 (head l>>4).
// ---------------------------------------------------------------------------
__device__ __forceinline__ float ent_score(const uint4& ent, int hA) {
  const unsigned uu = (hA < 2) ? ent.y : ent.z;
  const unsigned us = (hA & 1) ? (uu >> 16) : (uu & 0xffffu);
  return __half2float(__ushort_as_half((unsigned short)us));
}

__global__ __launch_bounds__(256) void k_agg(
    const unsigned* __restrict__ rs, const uint4* __restrict__ csr,
    const unsigned* __restrict__ xtb, float* __restrict__ out) {
  const int lane = threadIdx.x & 63;
  const int dst = (int)((blockIdx.x * (unsigned)blockDim.x + threadIdx.x) >> 6);
  if (dst >= N_NODES) return;

  const unsigned j0 = rs[dst];
  const unsigned j1 = rs[dst + 1];
  const int deg = (int)(j1 - j0);

  float a0 = 0.f, a1 = 0.f, lsum = 0.f;

  if (deg > 0) {
    const int rounds = (deg + 15) >> 4;
    const int sub = lane >> 2;   // edge-within-round in score space
    const int hA = lane & 3;     // head in score space
    const int hB = lane >> 4;    // head of this lane's output features

    for (int r = 0; r < rounds; ++r) {
      const int base = (int)j0 + r * 16;
      const int j = base + sub;
      uint4 ent;
      if (j < (int)j1) {
        ent = csr[j];
      } else {
        ent.x = 0u; ent.y = 0xfc00fc00u; ent.z = 0xfc00fc00u; ent.w = 0u;
      }
      const float w = __expf(ent_score(ent, hA));  // pad: exp(-inf)=0
      lsum += w;
      const int sx = (int)ent.x;
#pragma unroll
      for (int jj = 0; jj < 16; ++jj) {
        const int src = __shfl(sx, 4 * jj, 64);
        const float wj = __shfl(w, 4 * jj + hB, 64);
        const unsigned u = xtb[(size_t)src * 64 + lane];
        a0 = fmaf(wj, __uint_as_float(u << 16), a0);
        a1 = fmaf(wj, __uint_as_float(u & 0xffff0000u), a1);
      }
    }
    lsum += __shfl_xor(lsum, 4, 64);
    lsum += __shfl_xor(lsum, 8, 64);
    lsum += __shfl_xor(lsum, 16, 64);
    lsum += __shfl_xor(lsum, 32, 64);
    lsum = __shfl(lsum, hB, 64);   // lane hB holds head hB's sum
  }

  const float inv = 1.0f / (lsum + 1e-10f);
  out[(size_t)dst * 128 + lane * 2 + 0] = a0 * inv;
  out[(size_t)dst * 128 + lane * 2 + 1] = a1 * inv;
}

extern "C" void kernel_launch(void* const* d_in, const int* in_sizes, int n_in,
                              void* d_out, int out_size, void* d_ws,
                              size_t ws_size, hipStream_t stream) {
  const float* x = (const float*)d_in[0];
  const int* ei = (const int*)d_in[1];
  const float* ea = (const float*)d_in[2];
  const float* W = (const float*)d_in[3];
  const float* a = (const float*)d_in[4];
  float* out = (float*)d_out;

  // workspace layout
  char* p = (char*)d_ws;
  unsigned* xtb = (unsigned*)p;     p += (size_t)N_NODES * 64 * 4;    // 12.8 MB
  uint4* csr = (uint4*)p;           p += (size_t)N_EDGES * 16;        // 12.8 MB
  float* alpha_src = (float*)p;     p += (size_t)N_NODES * 4 * 4;     // 0.8 MB
  float* alpha_dst = (float*)p;     p += (size_t)N_NODES * 4 * 4;     // 0.8 MB
  unsigned* count = (unsigned*)p;   p += (size_t)N_NODES * 4;         // 0.2 MB
  unsigned* fill = (unsigned*)p;    p += (size_t)N_NODES * 4;         // 0.2 MB
  unsigned* rs = (unsigned*)p;      p += (size_t)(N_NODES + 1) * 4;
  unsigned* bsum = (unsigned*)p;    p += 64 * 4;
  unsigned* boff = (unsigned*)p;    p += 64 * 4;

  hipMemsetAsync(count, 0, (size_t)N_NODES * 4, stream);

  k_transform<<<(N_NODES + 63) / 64, 256, 0, stream>>>(x, W, a, xtb, alpha_src,
                                                       alpha_dst);
  k_hist<<<(N_EDGES + 255) / 256, 256, 0, stream>>>(ei, count);
  k_scan_a<<<N_SCAN_BLKS, SCAN_BLK, 0, stream>>>(count, rs, bsum);
  k_scan_b<<<1, 64, 0, stream>>>(bsum, boff);
  k_scan_c<<<N_SCAN_BLKS, SCAN_BLK, 0, stream>>>(rs, boff, fill);
  k_scatter<<<(N_EDGES + 255) / 256, 256, 0, stream>>>(
      ei, ea, a, alpha_src, alpha_dst, fill, csr);
  k_agg<<<(N_NODES * 64 + 255) / 256, 256, 0, stream>>>(rs, csr, xtb, out);
}